// Round 9
// baseline (205.568 us; speedup 1.0000x reference)
//
#include <hip/hip_runtime.h>
#include <math.h>

#define Bx 2
#define Sx 2048
#define Dx 1024
#define Hx 16
#define HDx 64
#define Mx (Bx*Sx)   // 4096

typedef __bf16 bf16x8 __attribute__((ext_vector_type(8)));
typedef __bf16 bf16x4 __attribute__((ext_vector_type(4)));
typedef float  f32x4  __attribute__((ext_vector_type(4)));
typedef _Float16 f16x8 __attribute__((ext_vector_type(8)));

// 0.125 (1/sqrt(64)) * log2(e): softmax in exp2 domain; folded into Q in GEMM1
#define SCL 0.18033688011112042f

__device__ __forceinline__ void gload_lds16(const __bf16* g, __bf16* l) {
  __builtin_amdgcn_global_load_lds(
      (const __attribute__((address_space(1))) unsigned int*)g,
      (__attribute__((address_space(3))) unsigned int*)l, 16, 0, 0);
}

// ---------------- fp32 -> bf16 conversion / weight concat ----------------
__device__ __forceinline__ void cvt8(const float* s, __bf16* d) {
  float4 a = *(const float4*)s;
  float4 b = *(const float4*)(s + 4);
  bf16x8 o;
  o[0] = (__bf16)a.x; o[1] = (__bf16)a.y; o[2] = (__bf16)a.z; o[3] = (__bf16)a.w;
  o[4] = (__bf16)b.x; o[5] = (__bf16)b.y; o[6] = (__bf16)b.z; o[7] = (__bf16)b.w;
  *(bf16x8*)d = o;
}

__global__ __launch_bounds__(256) void cvt_kernel(
    const float* __restrict__ x, const float* __restrict__ Wq,
    const float* __restrict__ Wk, const float* __restrict__ Wv,
    const float* __restrict__ Wo, const float* __restrict__ bq,
    const float* __restrict__ bk, const float* __restrict__ bv,
    __bf16* __restrict__ xb, __bf16* __restrict__ wqkv,
    __bf16* __restrict__ wob, float* __restrict__ bqkv)
{
  const int bid = blockIdx.x;
  const int t = threadIdx.x;
  const size_t MEG = 1024u * 1024u;
  if (bid < 2048) {
    size_t e = (size_t)bid * 2048 + t * 8;
    cvt8(x + e, xb + e);
  } else if (bid < 3584) {
    size_t e = (size_t)(bid - 2048) * 2048 + t * 8;
    const float* src = (e < MEG) ? (Wq + e) : (e < 2 * MEG) ? (Wk + (e - MEG)) : (Wv + (e - 2 * MEG));
    cvt8(src, wqkv + e);
  } else if (bid < 4096) {
    size_t e = (size_t)(bid - 3584) * 2048 + t * 8;
    cvt8(Wo + e, wob + e);
  } else {
    for (int i = t; i < 3072; i += 256)
      bqkv[i] = (i < 1024) ? bq[i] : (i < 2048) ? bk[i - 1024] : bv[i - 2048];
  }
}

// ---------------- bf16 MFMA GEMM: C[M,N] = A[M,K] @ W[N,K]^T + bias ----------------
// BK=64, XOR-swizzled LDS image via swizzled source addressing of
// global_load_lds. Epilogue stages C through LDS for 16B coalesced stores.
// MODE 0: fp32 out (ldc). MODE 1: bf16 qkv (Q pre-scaled by SCL) n0<2048;
// V tiles (n0>=2048) staged transposed -> coalesced vT.
template<int TM, int TN, int MODE>
__global__ __launch_bounds__(256) void gemm_k(
    const __bf16* __restrict__ A, const __bf16* __restrict__ W,
    const float* __restrict__ bias, float* __restrict__ Cf,
    __bf16* __restrict__ Cb, __bf16* __restrict__ vT,
    int M, int N, int K, int ldc)
{
  __shared__ __align__(16) char smem[35840];
  __bf16* As = (__bf16*)smem;
  __bf16* Bs = (__bf16*)(smem + (size_t)TM * 64 * 2);

  constexpr int MS = TM / 32;
  constexpr int NS = TN / 32;
  const int tid = threadIdx.x;
  const int lane = tid & 63, wave = tid >> 6;
  const int l16 = lane & 15, quad = lane >> 4;
  const int wm = (wave >> 1) * (TM / 2);
  const int wn = (wave & 1) * (TN / 2);
  const int m0 = blockIdx.y * TM;
  const int n0 = blockIdx.x * TN;
  const int swz = l16 & 7;

  const f32x4 zero = {0.f, 0.f, 0.f, 0.f};
  f32x4 acc[MS][NS];
#pragma unroll
  for (int i = 0; i < MS; ++i)
#pragma unroll
    for (int j = 0; j < NS; ++j) acc[i][j] = zero;

  const int srow = tid >> 3;
  const int scs = (tid & 7) ^ (srow & 7);
  const __bf16* Ag = A + (size_t)(m0 + srow) * K + scs * 8;
  const __bf16* Wg = W + (size_t)(n0 + srow) * K + scs * 8;

  for (int k0 = 0; k0 < K; k0 += 64) {
    __syncthreads();
#pragma unroll
    for (int i = 0; i < TM / 32; ++i)
      gload_lds16(Ag + (size_t)(i * 32) * K + k0, &As[(i * 256 + tid) * 8]);
#pragma unroll
    for (int i = 0; i < TN / 32; ++i)
      gload_lds16(Wg + (size_t)(i * 32) * K + k0, &Bs[(i * 256 + tid) * 8]);
    __syncthreads();

#pragma unroll
    for (int hk = 0; hk < 2; ++hk) {
      const int ph = ((hk * 4 + quad) ^ swz) * 8;
      bf16x8 af[MS], bfr[NS];
#pragma unroll
      for (int i = 0; i < MS; ++i)
        af[i] = *(const bf16x8*)&As[(wm + i * 16 + l16) * 64 + ph];
#pragma unroll
      for (int j = 0; j < NS; ++j)
        bfr[j] = *(const bf16x8*)&Bs[(wn + j * 16 + l16) * 64 + ph];
#pragma unroll
      for (int i = 0; i < MS; ++i)
#pragma unroll
        for (int j = 0; j < NS; ++j)
          acc[i][j] = __builtin_amdgcn_mfma_f32_16x16x32_bf16(af[i], bfr[j], acc[i][j], 0, 0, 0);
    }
  }

  __syncthreads();
  if (MODE == 0) {
    float* Cs = (float*)smem;          // [TM][TN+4]
    constexpr int cst = TN + 4;
#pragma unroll
    for (int j = 0; j < NS; ++j) {
      const int c = wn + j * 16 + l16;
      const float bv_ = bias[n0 + c];
#pragma unroll
      for (int i = 0; i < MS; ++i) {
        const int r0 = wm + i * 16 + quad * 4;
#pragma unroll
        for (int g = 0; g < 4; ++g)
          Cs[(r0 + g) * cst + c] = acc[i][j][g] + bv_;
      }
    }
    __syncthreads();
    constexpr int passes = TM * TN / (256 * 4);
#pragma unroll
    for (int p = 0; p < passes; ++p) {
      const int slot = p * 256 + tid;
      const int row = slot / (TN / 4);
      const int col4 = (slot % (TN / 4)) * 4;
      f32x4 v = *(const f32x4*)&Cs[row * cst + col4];
      *(f32x4*)&Cf[(size_t)(m0 + row) * ldc + n0 + col4] = v;
    }
  } else {
    __bf16* Cs = (__bf16*)smem;
    constexpr int cst = TN + 8;
    const bool vtile = (n0 >= 2048);
    if (!vtile) {
#pragma unroll
      for (int j = 0; j < NS; ++j) {
        const int c = wn + j * 16 + l16;
        const float bv_ = bias[n0 + c];
        const float sc = ((n0 + c) < 1024) ? SCL : 1.0f;
#pragma unroll
        for (int i = 0; i < MS; ++i) {
          const int r0 = wm + i * 16 + quad * 4;
#pragma unroll
          for (int g = 0; g < 4; ++g)
            Cs[(r0 + g) * cst + c] = (__bf16)((acc[i][j][g] + bv_) * sc);
        }
      }
      __syncthreads();
      constexpr int passes = TM * TN / (256 * 8);
#pragma unroll
      for (int p = 0; p < passes; ++p) {
        const int slot = p * 256 + tid;
        const int row = slot / (TN / 8);
        const int col8 = (slot % (TN / 8)) * 8;
        bf16x8 v = *(const bf16x8*)&Cs[row * cst + col8];
        *(bf16x8*)&Cb[(size_t)(m0 + row) * 3072 + n0 + col8] = v;
      }
    } else {
      constexpr int cstT = TM + 8;
#pragma unroll
      for (int j = 0; j < NS; ++j) {
        const int c = wn + j * 16 + l16;
        const float bv_ = bias[n0 + c];
#pragma unroll
        for (int i = 0; i < MS; ++i) {
          const int r0 = wm + i * 16 + quad * 4;
#pragma unroll
          for (int g = 0; g < 4; ++g)
            Cs[c * cstT + r0 + g] = (__bf16)(acc[i][j][g] + bv_);
        }
      }
      __syncthreads();
      const int bb = m0 >> 11, ml = m0 & 2047;
      constexpr int passes = TM * TN / (256 * 8);
#pragma unroll
      for (int p = 0; p < passes; ++p) {
        const int slot = p * 256 + tid;
        const int dd = slot / (TM / 8);
        const int ss8 = (slot % (TM / 8)) * 8;
        bf16x8 v = *(const bf16x8*)&Cs[dd * cstT + ss8];
        const int c2 = n0 - 2048 + dd;
        const int hh = c2 >> 6, ddd = c2 & 63;
        *(bf16x8*)&vT[((size_t)(bb * 16 + hh) * 64 + ddd) * 2048 + ml + ss8] = v;
      }
    }
  }
}

// ---------------- MFMA flash attention: 128-row Q-tile, 2 q-streams/wave ----
// No-max softmax (scores bounded; shift-invariance => exact same result).
// Each wave owns 32 q-rows as 2 independent 16-row streams: K/V LDS fragment
// reads are shared across both streams (halves the dominant LDS-read traffic).
// No S-pipelining (r7 lesson: S-state must stay <= 32 regs). K/V double-
// buffered at distance 1; one barrier per k-tile. l via ones-column MFMA.
// qt>=8 splits the key range across 2 blocks; partials (fp16 O, fp32 l) are
// summed by combine_kernel (valid because softmax here is shift-free).
// Diagonal spans the last TWO k-tiles (128-row q-tile) -> global-index mask.
__global__ __launch_bounds__(256, 3) void attn_mfma(
    const __bf16* __restrict__ qkv, const __bf16* __restrict__ vT,
    __bf16* __restrict__ zb, _Float16* __restrict__ Ph, float* __restrict__ Pl)
{
  __shared__ __bf16 Qs[128 * 64];     // Q; later per-wave 32-row P slices
  __shared__ __bf16 Ks[2][64 * 64];
  __shared__ __bf16 Vs[2][64 * 64];   // [d][k] (from vT)

  const int tid = threadIdx.x;
  const int lane = tid & 63, wave = tid >> 6;
  const int l16 = lane & 15, quad = lane >> 4;
  const int swz = l16 & 7;
  const int bx = blockIdx.x;
  const int bh = bx & 31;
  const int g = bx >> 5;              // 0..23
  int qt, half, split;
  if (g < 16) { split = 1; qt = 15 - (g >> 1); half = g & 1; }
  else        { split = 0; qt = g - 16; half = 0; }
  const int q0 = qt * 128;
  const int nk = 2 * qt + 2;
  const int t0 = (split && half) ? (qt + 1) : 0;
  const int t1 = (split && !half) ? (qt + 1) : nk;
  const int nt = t1 - t0;             // >= 2 always
  const int h = bh & 15, b = bh >> 4;

  const __bf16* qg = qkv + (size_t)b * 2048 * 3072 + h * 64;
  const __bf16* kg = qg + 1024;
  const __bf16* vg = vT + (size_t)bh * 64 * 2048;

#define STAGE_K8(kt_, kb)                                                       \
  { const int kn = (kt_) * 64;                                                  \
    _Pragma("unroll")                                                           \
    for (int i = 0; i < 2; ++i) {                                               \
      int slot = i * 256 + tid;                                                 \
      int row = slot >> 3;                                                      \
      int cs = (slot & 7) ^ (row & 7);                                          \
      gload_lds16(kg + (size_t)(kn + row) * 3072 + cs * 8, &Ks[kb][slot * 8]);  \
    } }
#define STAGE_V8(kt_, vb)                                                       \
  { const int kn = (kt_) * 64;                                                  \
    _Pragma("unroll")                                                           \
    for (int i = 0; i < 2; ++i) {                                               \
      int slot = i * 256 + tid;                                                 \
      int row = slot >> 3;                                                      \
      int cs = (slot & 7) ^ (row & 7);                                          \
      gload_lds16(vg + (size_t)row * 2048 + kn + cs * 8, &Vs[vb][slot * 8]);    \
    } }

  // prologue: Q (128 rows) + K/V tile t0
#pragma unroll
  for (int i = 0; i < 4; ++i) {
    int slot = i * 256 + tid;
    int row = slot >> 3;
    int cs = (slot & 7) ^ (row & 7);
    gload_lds16(qg + (size_t)(q0 + row) * 3072 + cs * 8, &Qs[slot * 8]);
  }
  STAGE_K8(t0, 0)
  STAGE_V8(t0, 0)
  __syncthreads();

  // Q fragments: 2 streams x 2 k-chunks, loop-invariant
  bf16x8 qf[2][2];
#pragma unroll
  for (int s = 0; s < 2; ++s)
#pragma unroll
    for (int kk = 0; kk < 2; ++kk)
      qf[s][kk] = *(const bf16x8*)&Qs[(wave * 32 + s * 16 + l16) * 64 + ((kk * 4 + quad) ^ swz) * 8];
  __bf16* P = &Qs[wave * 32 * 64];    // this wave's own 32x64 slice

  bf16x8 onesf;
  {
    __bf16 ov = (l16 == 0) ? (__bf16)1.0f : (__bf16)0.0f;
#pragma unroll
    for (int i = 0; i < 8; ++i) onesf[i] = ov;
  }

  const f32x4 zero = {0.f, 0.f, 0.f, 0.f};
  f32x4 O[2][4], Ol[2];
#pragma unroll
  for (int s = 0; s < 2; ++s) {
    Ol[s] = zero;
#pragma unroll
    for (int j = 0; j < 4; ++j) O[s][j] = zero;
  }

  for (int u = 0; u < nt; ++u) {
    const int kt = t0 + u;
    const int kb = u & 1;
    if (u + 1 < nt) {
      STAGE_K8(kt + 1, kb ^ 1)
      STAGE_V8(kt + 1, kb ^ 1)
    }
    // S = Q @ K^T, both streams sharing each K fragment
    f32x4 sv[2][4];
#pragma unroll
    for (int s = 0; s < 2; ++s)
#pragma unroll
      for (int j = 0; j < 4; ++j) sv[s][j] = zero;
#pragma unroll
    for (int kk = 0; kk < 2; ++kk) {
      const int ph = ((kk * 4 + quad) ^ swz) * 8;
#pragma unroll
      for (int j = 0; j < 4; ++j) {
        bf16x8 kf = *(const bf16x8*)&Ks[kb][(j * 16 + l16) * 64 + ph];
        sv[0][j] = __builtin_amdgcn_mfma_f32_16x16x32_bf16(qf[0][kk], kf, sv[0][j], 0, 0, 0);
        sv[1][j] = __builtin_amdgcn_mfma_f32_16x16x32_bf16(qf[1][kk], kf, sv[1][j], 0, 0, 0);
      }
    }
    // exp2 + causal mask (only the last two k-tiles can cross the diagonal)
    const bool md = (kt >= 2 * qt);
#pragma unroll
    for (int s = 0; s < 2; ++s)
#pragma unroll
      for (int j = 0; j < 4; ++j) {
        const int cg = kt * 64 + j * 16 + l16;
        const int rg = q0 + wave * 32 + s * 16 + quad * 4;
#pragma unroll
        for (int gg = 0; gg < 4; ++gg) {
          float p = __builtin_exp2f(sv[s][j][gg]);
          if (md && cg > rg + gg) p = 0.f;
          sv[s][j][gg] = p;
        }
      }
    // P -> bf16 -> this wave's LDS slice (A-frag source layout, swizzled)
#pragma unroll
    for (int s = 0; s < 2; ++s)
#pragma unroll
      for (int j = 0; j < 4; ++j) {
        const int col = j * 16 + l16;
        const int ch = col >> 3, cin = col & 7;
#pragma unroll
        for (int gg = 0; gg < 4; ++gg) {
          const int rl = s * 16 + quad * 4 + gg;
          P[rl * 64 + ((ch ^ (rl & 7)) * 8) + cin] = (__bf16)sv[s][j][gg];
        }
      }
    // O += P @ V (in-wave LDS RAW: DS ops in-order per wave)
#pragma unroll
    for (int kk = 0; kk < 2; ++kk) {
      const int ph = ((kk * 4 + quad) ^ swz) * 8;
      bf16x8 pf0 = *(const bf16x8*)&P[l16 * 64 + ph];
      bf16x8 pf1 = *(const bf16x8*)&P[(16 + l16) * 64 + ph];
#pragma unroll
      for (int j = 0; j < 4; ++j) {
        bf16x8 vf = *(const bf16x8*)&Vs[kb][(j * 16 + l16) * 64 + ph];
        O[0][j] = __builtin_amdgcn_mfma_f32_16x16x32_bf16(pf0, vf, O[0][j], 0, 0, 0);
        O[1][j] = __builtin_amdgcn_mfma_f32_16x16x32_bf16(pf1, vf, O[1][j], 0, 0, 0);
      }
      Ol[0] = __builtin_amdgcn_mfma_f32_16x16x32_bf16(pf0, onesf, Ol[0], 0, 0, 0);
      Ol[1] = __builtin_amdgcn_mfma_f32_16x16x32_bf16(pf1, onesf, Ol[1], 0, 0, 0);
    }
    if (u + 1 < nt) __syncthreads();
  }

  // epilogue
  if (!split) {
#pragma unroll
    for (int s = 0; s < 2; ++s)
#pragma unroll
      for (int gg = 0; gg < 4; ++gg) {
        const float lv = __shfl(Ol[s][gg], quad * 16);  // col 0 of Ol
        const float inv = 1.0f / lv;
        const int rq = q0 + wave * 32 + s * 16 + quad * 4 + gg;
        const size_t rb = (size_t)(b * 2048 + rq) * 1024 + h * 64 + l16;
#pragma unroll
        for (int j = 0; j < 4; ++j)
          zb[rb + j * 16] = (__bf16)(O[s][j][gg] * inv);
      }
  } else {
    const int p2 = ((bh << 3) + (qt - 8)) * 2 + half;
    _Float16* Op = Ph + (size_t)p2 * 8192;   // [128][64]
    float* Lp = Pl + (size_t)p2 * 128;
#pragma unroll
    for (int s = 0; s < 2; ++s)
#pragma unroll
      for (int gg = 0; gg < 4; ++gg) {
        const int rl = wave * 32 + s * 16 + quad * 4 + gg;
#pragma unroll
        for (int j = 0; j < 4; ++j)
          Op[rl * 64 + j * 16 + l16] = (_Float16)O[s][j][gg];
        if (l16 == 0) Lp[rl] = Ol[s][gg];
      }
  }
}

// ---------------- combine split-k partials -> zb ----------------
__global__ __launch_bounds__(256) void combine_kernel(
    const _Float16* __restrict__ Ph, const float* __restrict__ Pl,
    __bf16* __restrict__ zb)
{
  const int bxx = blockIdx.x;          // 0..511
  const int st = bxx >> 1, sub = bxx & 1;
  const int bh = st >> 3, qi = st & 7;
  const int qt = 8 + qi;
  const int b = bh >> 4, h = bh & 15;
  const int p0 = st * 2;
  const _Float16* O0 = Ph + (size_t)p0 * 8192;
  const _Float16* O1 = O0 + 8192;
  const float* L0 = Pl + (size_t)p0 * 128;
  const float* L1 = L0 + 128;
  const int r = sub * 64 + (threadIdx.x >> 2);       // 0..127
  const int c0 = (threadIdx.x & 3) * 16;
  const float inv = 1.0f / (L0[r] + L1[r]);
  const size_t base = (size_t)(b * 2048 + qt * 128 + r) * 1024 + h * 64 + c0;
#pragma unroll
  for (int u = 0; u < 2; ++u) {
    f16x8 a = *(const f16x8*)&O0[r * 64 + c0 + u * 8];
    f16x8 c = *(const f16x8*)&O1[r * 64 + c0 + u * 8];
    bf16x8 o;
#pragma unroll
    for (int i = 0; i < 8; ++i)
      o[i] = (__bf16)(((float)a[i] + (float)c[i]) * inv);
    *(bf16x8*)&zb[base + u * 8] = o;
  }
}

// ---------------- launch ----------------
extern "C" void kernel_launch(void* const* d_in, const int* in_sizes, int n_in,
                              void* d_out, int out_size, void* d_ws, size_t ws_size,
                              hipStream_t stream) {
  (void)in_sizes; (void)n_in; (void)out_size; (void)ws_size;
  const float* x  = (const float*)d_in[0];
  const float* Wq = (const float*)d_in[1];
  const float* bq = (const float*)d_in[2];
  const float* Wk = (const float*)d_in[3];
  const float* bk = (const float*)d_in[4];
  const float* Wv = (const float*)d_in[5];
  const float* bv = (const float*)d_in[6];
  const float* Wo = (const float*)d_in[7];
  const float* bo = (const float*)d_in[8];

  char* ws = (char*)d_ws;
  __bf16* xb   = (__bf16*)(ws);                        // 8 MB (dead after GEMM1)
  __bf16* wqkv = (__bf16*)(ws + (8ull  << 20));        // 6 MB (dead after GEMM1)
  __bf16* wob  = (__bf16*)(ws + (14ull << 20));        // 2 MB
  float*  bqkv = (float*) (ws + (16ull << 20));        // 12 KB
  __bf16* qkv  = (__bf16*)(ws + (17ull << 20));        // 24 MB
  __bf16* vT   = (__bf16*)(ws + (41ull << 20));        // 8 MB  [bh][64][2048]
  __bf16* zb   = (__bf16*)(ws + (49ull << 20));        // 8 MB
  // split-k partials reuse the xb/wqkv region (free once GEMM1 is done):
  _Float16* Ph = (_Float16*)(ws);                      // 512 x 8192 f16 = 8 MB
  float*    Pl = (float*)(ws + (8ull << 20) + (512ull << 10));  // 256 KB

  cvt_kernel<<<4097, 256, 0, stream>>>(x, Wq, Wk, Wv, Wo, bq, bk, bv,
                                       xb, wqkv, wob, bqkv);
  gemm_k<128, 128, 1><<<dim3(24, 32), 256, 0, stream>>>(
      xb, wqkv, bqkv, nullptr, qkv, vT, Mx, 3072, 1024, 0);
  attn_mfma<<<768, 256, 0, stream>>>(qkv, vT, zb, Ph, Pl);
  combine_kernel<<<512, 256, 0, stream>>>(Ph, Pl, zb);
  gemm_k<128, 64, 0><<<dim3(16, 32), 256, 0, stream>>>(
      zb, wob, bo, (float*)d_out, nullptr, nullptr, Mx, 1024, 1024, 1024);
}

// Round 10
// 191.348 us; speedup vs baseline: 1.0743x; 1.0743x over previous
//
#include <hip/hip_runtime.h>
#include <math.h>

#define Bx 2
#define Sx 2048
#define Dx 1024
#define Hx 16
#define HDx 64
#define Mx (Bx*Sx)   // 4096

typedef __bf16 bf16x8 __attribute__((ext_vector_type(8)));
typedef __bf16 bf16x4 __attribute__((ext_vector_type(4)));
typedef float  f32x4  __attribute__((ext_vector_type(4)));

// 0.125 (1/sqrt(64)) * log2(e): softmax in exp2 domain; folded into Q in GEMM1
#define SCL 0.18033688011112042f

__device__ __forceinline__ void gload_lds16(const __bf16* g, __bf16* l) {
  __builtin_amdgcn_global_load_lds(
      (const __attribute__((address_space(1))) unsigned int*)g,
      (__attribute__((address_space(3))) unsigned int*)l, 16, 0, 0);
}

// ---------------- fp32 -> bf16 conversion / weight concat ----------------
__device__ __forceinline__ void cvt8(const float* s, __bf16* d) {
  float4 a = *(const float4*)s;
  float4 b = *(const float4*)(s + 4);
  bf16x8 o;
  o[0] = (__bf16)a.x; o[1] = (__bf16)a.y; o[2] = (__bf16)a.z; o[3] = (__bf16)a.w;
  o[4] = (__bf16)b.x; o[5] = (__bf16)b.y; o[6] = (__bf16)b.z; o[7] = (__bf16)b.w;
  *(bf16x8*)d = o;
}

__global__ __launch_bounds__(256) void cvt_kernel(
    const float* __restrict__ x, const float* __restrict__ Wq,
    const float* __restrict__ Wk, const float* __restrict__ Wv,
    const float* __restrict__ Wo, const float* __restrict__ bq,
    const float* __restrict__ bk, const float* __restrict__ bv,
    __bf16* __restrict__ xb, __bf16* __restrict__ wqkv,
    __bf16* __restrict__ wob, float* __restrict__ bqkv)
{
  const int bid = blockIdx.x;
  const int t = threadIdx.x;
  const size_t MEG = 1024u * 1024u;
  if (bid < 2048) {
    size_t e = (size_t)bid * 2048 + t * 8;
    cvt8(x + e, xb + e);
  } else if (bid < 3584) {
    size_t e = (size_t)(bid - 2048) * 2048 + t * 8;
    const float* src = (e < MEG) ? (Wq + e) : (e < 2 * MEG) ? (Wk + (e - MEG)) : (Wv + (e - 2 * MEG));
    cvt8(src, wqkv + e);
  } else if (bid < 4096) {
    size_t e = (size_t)(bid - 3584) * 2048 + t * 8;
    cvt8(Wo + e, wob + e);
  } else {
    for (int i = t; i < 3072; i += 256)
      bqkv[i] = (i < 1024) ? bq[i] : (i < 2048) ? bk[i - 1024] : bv[i - 2048];
  }
}

// ---------------- bf16 MFMA GEMM: C[M,N] = A[M,K] @ W[N,K]^T + bias ----------------
// BK=64, XOR-swizzled LDS image via swizzled source addressing of
// global_load_lds. Epilogue stages C through LDS for 16B coalesced stores.
// MODE 0: fp32 out (ldc). MODE 1: bf16 qkv (Q pre-scaled by SCL) n0<2048;
// V tiles (n0>=2048) staged transposed -> coalesced vT.
template<int TM, int TN, int MODE>
__global__ __launch_bounds__(256) void gemm_k(
    const __bf16* __restrict__ A, const __bf16* __restrict__ W,
    const float* __restrict__ bias, float* __restrict__ Cf,
    __bf16* __restrict__ Cb, __bf16* __restrict__ vT,
    int M, int N, int K, int ldc)
{
  __shared__ __align__(16) char smem[35840];
  __bf16* As = (__bf16*)smem;
  __bf16* Bs = (__bf16*)(smem + (size_t)TM * 64 * 2);

  constexpr int MS = TM / 32;
  constexpr int NS = TN / 32;
  const int tid = threadIdx.x;
  const int lane = tid & 63, wave = tid >> 6;
  const int l16 = lane & 15, quad = lane >> 4;
  const int wm = (wave >> 1) * (TM / 2);
  const int wn = (wave & 1) * (TN / 2);
  const int m0 = blockIdx.y * TM;
  const int n0 = blockIdx.x * TN;
  const int swz = l16 & 7;

  const f32x4 zero = {0.f, 0.f, 0.f, 0.f};
  f32x4 acc[MS][NS];
#pragma unroll
  for (int i = 0; i < MS; ++i)
#pragma unroll
    for (int j = 0; j < NS; ++j) acc[i][j] = zero;

  const int srow = tid >> 3;
  const int scs = (tid & 7) ^ (srow & 7);
  const __bf16* Ag = A + (size_t)(m0 + srow) * K + scs * 8;
  const __bf16* Wg = W + (size_t)(n0 + srow) * K + scs * 8;

  for (int k0 = 0; k0 < K; k0 += 64) {
    __syncthreads();
#pragma unroll
    for (int i = 0; i < TM / 32; ++i)
      gload_lds16(Ag + (size_t)(i * 32) * K + k0, &As[(i * 256 + tid) * 8]);
#pragma unroll
    for (int i = 0; i < TN / 32; ++i)
      gload_lds16(Wg + (size_t)(i * 32) * K + k0, &Bs[(i * 256 + tid) * 8]);
    __syncthreads();

#pragma unroll
    for (int hk = 0; hk < 2; ++hk) {
      const int ph = ((hk * 4 + quad) ^ swz) * 8;
      bf16x8 af[MS], bfr[NS];
#pragma unroll
      for (int i = 0; i < MS; ++i)
        af[i] = *(const bf16x8*)&As[(wm + i * 16 + l16) * 64 + ph];
#pragma unroll
      for (int j = 0; j < NS; ++j)
        bfr[j] = *(const bf16x8*)&Bs[(wn + j * 16 + l16) * 64 + ph];
#pragma unroll
      for (int i = 0; i < MS; ++i)
#pragma unroll
        for (int j = 0; j < NS; ++j)
          acc[i][j] = __builtin_amdgcn_mfma_f32_16x16x32_bf16(af[i], bfr[j], acc[i][j], 0, 0, 0);
    }
  }

  __syncthreads();
  if (MODE == 0) {
    float* Cs = (float*)smem;          // [TM][TN+4]
    constexpr int cst = TN + 4;
#pragma unroll
    for (int j = 0; j < NS; ++j) {
      const int c = wn + j * 16 + l16;
      const float bv_ = bias[n0 + c];
#pragma unroll
      for (int i = 0; i < MS; ++i) {
        const int r0 = wm + i * 16 + quad * 4;
#pragma unroll
        for (int g = 0; g < 4; ++g)
          Cs[(r0 + g) * cst + c] = acc[i][j][g] + bv_;
      }
    }
    __syncthreads();
    constexpr int passes = TM * TN / (256 * 4);
#pragma unroll
    for (int p = 0; p < passes; ++p) {
      const int slot = p * 256 + tid;
      const int row = slot / (TN / 4);
      const int col4 = (slot % (TN / 4)) * 4;
      f32x4 v = *(const f32x4*)&Cs[row * cst + col4];
      *(f32x4*)&Cf[(size_t)(m0 + row) * ldc + n0 + col4] = v;
    }
  } else {
    __bf16* Cs = (__bf16*)smem;
    constexpr int cst = TN + 8;
    const bool vtile = (n0 >= 2048);
    if (!vtile) {
#pragma unroll
      for (int j = 0; j < NS; ++j) {
        const int c = wn + j * 16 + l16;
        const float bv_ = bias[n0 + c];
        const float sc = ((n0 + c) < 1024) ? SCL : 1.0f;
#pragma unroll
        for (int i = 0; i < MS; ++i) {
          const int r0 = wm + i * 16 + quad * 4;
#pragma unroll
          for (int g = 0; g < 4; ++g)
            Cs[(r0 + g) * cst + c] = (__bf16)((acc[i][j][g] + bv_) * sc);
        }
      }
      __syncthreads();
      constexpr int passes = TM * TN / (256 * 8);
#pragma unroll
      for (int p = 0; p < passes; ++p) {
        const int slot = p * 256 + tid;
        const int row = slot / (TN / 8);
        const int col8 = (slot % (TN / 8)) * 8;
        bf16x8 v = *(const bf16x8*)&Cs[row * cst + col8];
        *(bf16x8*)&Cb[(size_t)(m0 + row) * 3072 + n0 + col8] = v;
      }
    } else {
      constexpr int cstT = TM + 8;
#pragma unroll
      for (int j = 0; j < NS; ++j) {
        const int c = wn + j * 16 + l16;
        const float bv_ = bias[n0 + c];
#pragma unroll
        for (int i = 0; i < MS; ++i) {
          const int r0 = wm + i * 16 + quad * 4;
#pragma unroll
          for (int g = 0; g < 4; ++g)
            Cs[c * cstT + r0 + g] = (__bf16)(acc[i][j][g] + bv_);
        }
      }
      __syncthreads();
      const int bb = m0 >> 11, ml = m0 & 2047;
      constexpr int passes = TM * TN / (256 * 8);
#pragma unroll
      for (int p = 0; p < passes; ++p) {
        const int slot = p * 256 + tid;
        const int dd = slot / (TM / 8);
        const int ss8 = (slot % (TM / 8)) * 8;
        bf16x8 v = *(const bf16x8*)&Cs[dd * cstT + ss8];
        const int c2 = n0 - 2048 + dd;
        const int hh = c2 >> 6, ddd = c2 & 63;
        *(bf16x8*)&vT[((size_t)(bb * 16 + hh) * 64 + ddd) * 2048 + ml + ss8] = v;
      }
    }
  }
}

// ---------------- MFMA flash attention, S^T formulation ----------------
// S^T = K.Q^T (operand swap, free): C-layout then gives each lane P values
// for ONE q-row (col=l16) and contiguous key groups, so the P->A-layout
// transpose is 4x ds_write_b64 of packed bf16 pairs instead of 16 scattered
// ds_write_b16. P read-back, O layout, ones-MFMA l-trick, epilogue all
// unchanged from r6/r8. No-max softmax (scores bounded; shift-invariant).
// S pipelined one tile ahead; K dbuf (dist 2), V triple-buf. One barrier/tile.
__global__ __launch_bounds__(256) void attn_mfma(
    const __bf16* __restrict__ qkv, const __bf16* __restrict__ vT,
    __bf16* __restrict__ zb)
{
  __shared__ __bf16 Qs[64 * 64];      // Q; later per-wave P slices
  __shared__ __bf16 Ks[2][64 * 64];
  __shared__ __bf16 Vs[3][64 * 64];   // [d][k] (from vT)

  const int tid = threadIdx.x;
  const int lane = tid & 63, wave = tid >> 6;
  const int l16 = lane & 15, quad = lane >> 4;
  const int bx = blockIdx.x;
  const int qt = 31 - (bx >> 5);       // heavy q-tiles dispatched first
  const int bh = bx & 31;
  const int h = bh & 15, b = bh >> 4;
  const int q0 = qt * 64;

  const __bf16* qg = qkv + (size_t)b * 2048 * 3072 + h * 64;
  const __bf16* kg = qg + 1024;
  const __bf16* vg = vT + (size_t)bh * 64 * 2048;

#define STAGE_KV(kt_, kbuf, vbuf)                                               \
  { const int kn = (kt_) * 64;                                                  \
    _Pragma("unroll")                                                           \
    for (int i = 0; i < 2; ++i) {                                               \
      int slot = i * 256 + tid;                                                 \
      int row = slot >> 3, ph2 = slot & 7;                                      \
      int cs = ph2 ^ (row & 7);                                                 \
      gload_lds16(kg + (size_t)(kn + row) * 3072 + cs * 8, &Ks[kbuf][slot * 8]);\
      gload_lds16(vg + (size_t)row * 2048 + kn + cs * 8, &Vs[vbuf][slot * 8]);  \
    } }

  // prologue: Q + K/V tile 0
#pragma unroll
  for (int i = 0; i < 2; ++i) {
    int slot = i * 256 + tid;
    int row = slot >> 3, ph2 = slot & 7;
    int cs = ph2 ^ (row & 7);
    gload_lds16(qg + (size_t)(q0 + row) * 3072 + cs * 8, &Qs[slot * 8]);
  }
  STAGE_KV(0, 0, 0)
  __syncthreads();

  const int swz = l16 & 7;
  const int sw0 = ((quad) ^ swz) * 8;
  const int sw1 = ((quad + 4) ^ swz) * 8;
  const int mrow = wave * 16 + l16;

  // Q fragments (loop-invariant), used as the B operand of S^T = K.Q^T
  bf16x8 qf0 = *(const bf16x8*)&Qs[mrow * 64 + sw0];
  bf16x8 qf1 = *(const bf16x8*)&Qs[mrow * 64 + sw1];
  __bf16* P = &Qs[wave * 16 * 64];    // this wave's own 16x64 slice

  // ones B-frag: B[n=0][k]=1 -> col 0 of Ol = row-sum of P (the l vector)
  bf16x8 onesf;
  {
    __bf16 ov = (l16 == 0) ? (__bf16)1.0f : (__bf16)0.0f;
#pragma unroll
    for (int i = 0; i < 8; ++i) onesf[i] = ov;
  }

  const f32x4 zero = {0.f, 0.f, 0.f, 0.f};
  f32x4 O[4], Ol = zero;
#pragma unroll
  for (int j = 0; j < 4; ++j) O[j] = zero;
  f32x4 s_cur[4], s_next[4];   // S^T: index m = key block; lane: [key=m*16+quad*4+g][q=l16]

#define S_TILE(sdst, kb)                                                        \
  { _Pragma("unroll")                                                           \
    for (int m = 0; m < 4; ++m) sdst[m] = zero;                                 \
    _Pragma("unroll")                                                           \
    for (int m = 0; m < 4; ++m) {                                               \
      bf16x8 kf0 = *(const bf16x8*)&Ks[kb][(m * 16 + l16) * 64 + sw0];          \
      sdst[m] = __builtin_amdgcn_mfma_f32_16x16x32_bf16(kf0, qf0, sdst[m],0,0,0);\
      bf16x8 kf1 = *(const bf16x8*)&Ks[kb][(m * 16 + l16) * 64 + sw1];          \
      sdst[m] = __builtin_amdgcn_mfma_f32_16x16x32_bf16(kf1, qf1, sdst[m],0,0,0);\
    } }

// exp2 + (optional) causal mask + packed b64 P-write.
// Lane holds P[q=l16][key=m*16+quad*4+g]; keys quad*4..+3 are contiguous ->
// one bf16x4 (8B) store per m. Chunk swizzle (16B units): phys = c ^ (l16&7),
// c = 2m + (quad>>1), in-chunk offset (quad&1)*4 bf16. Reads unswizzle same.
#define EXP_P(s, DIAG)                                                          \
  { _Pragma("unroll")                                                           \
    for (int m = 0; m < 4; ++m) {                                               \
      const int kl = m * 16 + quad * 4;                                         \
      bf16x4 st;                                                                \
      _Pragma("unroll")                                                         \
      for (int g = 0; g < 4; ++g) {                                             \
        float p = __builtin_exp2f(s[m][g]);                                     \
        if (DIAG && (kl + g) > (wave * 16 + l16)) p = 0.f;                      \
        st[g] = (__bf16)p;                                                      \
      }                                                                         \
      *(bf16x4*)&P[l16 * 64 + (((2 * m + (quad >> 1)) ^ swz) * 8) + (quad & 1) * 4] = st; \
    } }

#define PV_TILE(vb)                                                             \
  { bf16x8 pf0 = *(const bf16x8*)&P[l16 * 64 + sw0];                            \
    bf16x8 pf1 = *(const bf16x8*)&P[l16 * 64 + sw1];                            \
    _Pragma("unroll")                                                           \
    for (int j = 0; j < 4; ++j) {                                               \
      bf16x8 vf0 = *(const bf16x8*)&Vs[vb][(j * 16 + l16) * 64 + sw0];          \
      O[j] = __builtin_amdgcn_mfma_f32_16x16x32_bf16(pf0, vf0, O[j], 0, 0, 0);  \
      bf16x8 vf1 = *(const bf16x8*)&Vs[vb][(j * 16 + l16) * 64 + sw1];          \
      O[j] = __builtin_amdgcn_mfma_f32_16x16x32_bf16(pf1, vf1, O[j], 0, 0, 0);  \
    }                                                                           \
    Ol = __builtin_amdgcn_mfma_f32_16x16x32_bf16(pf0, onesf, Ol, 0, 0, 0);      \
    Ol = __builtin_amdgcn_mfma_f32_16x16x32_bf16(pf1, onesf, Ol, 0, 0, 0); }

  // pipeline prologue: stage tile 1, compute S^T(0)
  if (qt > 0) STAGE_KV(1, 1, 1)
  S_TILE(s_cur, 0)
  if (qt > 0) __syncthreads();   // drains stage(1)

  for (int t = 0; t < qt; ++t) {
    EXP_P(s_cur, false)                    // VALU of tile t ...
    S_TILE(s_next, (t + 1) & 1)            // ... overlaps MFMA of tile t+1
    PV_TILE(t % 3)
    if (t + 2 <= qt) STAGE_KV(t + 2, t & 1, (t + 2) % 3)
    __syncthreads();
#pragma unroll
    for (int m = 0; m < 4; ++m) s_cur[m] = s_next[m];
  }
  // diagonal (masked) tile
  EXP_P(s_cur, true)
  PV_TILE(qt % 3)

  // epilogue: l lives in col 0 of Ol (lanes l16==0); broadcast within quad
  const int rq = q0 + wave * 16 + quad * 4;
#pragma unroll
  for (int g = 0; g < 4; ++g) {
    const float lv = __shfl(Ol[g], quad * 16);
    const float inv = 1.0f / lv;
    const size_t rb = (size_t)(b * 2048 + rq + g) * 1024 + h * 64 + l16;
#pragma unroll
    for (int j = 0; j < 4; ++j)
      zb[rb + j * 16] = (__bf16)(O[j][g] * inv);
  }
}

// ---------------- launch ----------------
extern "C" void kernel_launch(void* const* d_in, const int* in_sizes, int n_in,
                              void* d_out, int out_size, void* d_ws, size_t ws_size,
                              hipStream_t stream) {
  (void)in_sizes; (void)n_in; (void)out_size; (void)ws_size;
  const float* x  = (const float*)d_in[0];
  const float* Wq = (const float*)d_in[1];
  const float* bq = (const float*)d_in[2];
  const float* Wk = (const float*)d_in[3];
  const float* bk = (const float*)d_in[4];
  const float* Wv = (const float*)d_in[5];
  const float* bv = (const float*)d_in[6];
  const float* Wo = (const float*)d_in[7];
  const float* bo = (const float*)d_in[8];

  char* ws = (char*)d_ws;
  __bf16* xb   = (__bf16*)(ws);                        // 8 MB
  __bf16* wqkv = (__bf16*)(ws + (8ull  << 20));        // 6 MB
  __bf16* wob  = (__bf16*)(ws + (14ull << 20));        // 2 MB
  float*  bqkv = (float*) (ws + (16ull << 20));        // 12 KB
  __bf16* qkv  = (__bf16*)(ws + (17ull << 20));        // 24 MB
  __bf16* vT   = (__bf16*)(ws + (41ull << 20));        // 8 MB  [bh][64][2048]
  __bf16* zb   = (__bf16*)(ws + (49ull << 20));        // 8 MB  (total 57 MB)

  cvt_kernel<<<4097, 256, 0, stream>>>(x, Wq, Wk, Wv, Wo, bq, bk, bv,
                                       xb, wqkv, wob, bqkv);
  gemm_k<128, 128, 1><<<dim3(24, 32), 256, 0, stream>>>(
      xb, wqkv, bqkv, nullptr, qkv, vT, Mx, 3072, 1024, 0);
  attn_mfma<<<1024, 256, 0, stream>>>(qkv, vT, zb);
  gemm_k<128, 64, 0><<<dim3(16, 32), 256, 0, stream>>>(
      zb, wob, bo, (float*)d_out, nullptr, nullptr, Mx, 1024, 1024, 1024);
}

// Round 11
// 180.559 us; speedup vs baseline: 1.1385x; 1.0598x over previous
//
#include <hip/hip_runtime.h>
#include <math.h>

#define Bx 2
#define Sx 2048
#define Dx 1024
#define Hx 16
#define HDx 64
#define Mx (Bx*Sx)   // 4096

typedef __bf16 bf16x8 __attribute__((ext_vector_type(8)));
typedef __bf16 bf16x4 __attribute__((ext_vector_type(4)));
typedef float  f32x4  __attribute__((ext_vector_type(4)));

// 0.125 (1/sqrt(64)) * log2(e): softmax in exp2 domain; folded into Q in GEMM1
#define SCL 0.18033688011112042f

__device__ __forceinline__ void gload_lds16(const __bf16* g, __bf16* l) {
  __builtin_amdgcn_global_load_lds(
      (const __attribute__((address_space(1))) unsigned int*)g,
      (__attribute__((address_space(3))) unsigned int*)l, 16, 0, 0);
}

// ---------------- fp32 -> bf16 conversion / weight concat ----------------
__device__ __forceinline__ void cvt8(const float* s, __bf16* d) {
  float4 a = *(const float4*)s;
  float4 b = *(const float4*)(s + 4);
  bf16x8 o;
  o[0] = (__bf16)a.x; o[1] = (__bf16)a.y; o[2] = (__bf16)a.z; o[3] = (__bf16)a.w;
  o[4] = (__bf16)b.x; o[5] = (__bf16)b.y; o[6] = (__bf16)b.z; o[7] = (__bf16)b.w;
  *(bf16x8*)d = o;
}

__global__ __launch_bounds__(256) void cvt_kernel(
    const float* __restrict__ x, const float* __restrict__ Wq,
    const float* __restrict__ Wk, const float* __restrict__ Wv,
    const float* __restrict__ Wo, const float* __restrict__ bq,
    const float* __restrict__ bk, const float* __restrict__ bv,
    __bf16* __restrict__ xb, __bf16* __restrict__ wqkv,
    __bf16* __restrict__ wob, float* __restrict__ bqkv)
{
  const int bid = blockIdx.x;
  const int t = threadIdx.x;
  const size_t MEG = 1024u * 1024u;
  if (bid < 2048) {
    size_t e = (size_t)bid * 2048 + t * 8;
    cvt8(x + e, xb + e);
  } else if (bid < 3584) {
    size_t e = (size_t)(bid - 2048) * 2048 + t * 8;
    const float* src = (e < MEG) ? (Wq + e) : (e < 2 * MEG) ? (Wk + (e - MEG)) : (Wv + (e - 2 * MEG));
    cvt8(src, wqkv + e);
  } else if (bid < 4096) {
    size_t e = (size_t)(bid - 3584) * 2048 + t * 8;
    cvt8(Wo + e, wob + e);
  } else {
    for (int i = t; i < 3072; i += 256)
      bqkv[i] = (i < 1024) ? bq[i] : (i < 2048) ? bk[i - 1024] : bv[i - 2048];
  }
}

// ---------------- bf16 MFMA GEMM, stage-ahead pipelined ----------------
// BK=64, double-buffered LDS staging at distance 1: stage(t+1) DMA issues at
// the top of iter t, compute(t) overlaps the load latency, ONE barrier/iter
// (attn kernel's proven pattern). 64-block (8m x 8n) supertile swizzle keeps
// each XCD's staging working set (~1 A-panel + 8 W-panels ~ 2.3 MB) inside
// its 4 MB L2. Epilogue stages C through LDS for 16B coalesced stores.
// MODE 0: fp32 out (ldc). MODE 1: bf16 qkv (Q pre-scaled by SCL) n0<2048;
// V tiles (n0>=2048) staged transposed -> coalesced vT.
template<int TM, int TN, int MODE>
__global__ __launch_bounds__(256) void gemm_k(
    const __bf16* __restrict__ A, const __bf16* __restrict__ W,
    const float* __restrict__ bias, float* __restrict__ Cf,
    __bf16* __restrict__ Cb, __bf16* __restrict__ vT,
    int M, int N, int K, int ldc)
{
  __shared__ __align__(16) char smem[2 * (TM + TN) * 64 * 2];
  __bf16* AsB = (__bf16*)smem;

  constexpr int MS = TM / 32;
  constexpr int NS = TN / 32;
  const int tid = threadIdx.x;
  const int lane = tid & 63, wave = tid >> 6;
  const int l16 = lane & 15, quad = lane >> 4;
  const int wm = (wave >> 1) * (TM / 2);
  const int wn = (wave & 1) * (TN / 2);
  const int swz = l16 & 7;

  // 64-block supertile swizzle (8 m-tiles x 8 n-tiles)
  const int lid = blockIdx.y * gridDim.x + blockIdx.x;
  const int g8 = lid >> 6;
  const int r64 = lid & 63;
  const int gpm = (int)gridDim.y >> 3;
  const int gm = g8 % gpm;
  const int gn = g8 / gpm;
  const int m0 = (gm * 8 + (r64 & 7)) * TM;
  const int n0 = (gn * 8 + (r64 >> 3)) * TN;

  const f32x4 zero = {0.f, 0.f, 0.f, 0.f};
  f32x4 acc[MS][NS];
#pragma unroll
  for (int i = 0; i < MS; ++i)
#pragma unroll
    for (int j = 0; j < NS; ++j) acc[i][j] = zero;

  const int srow = tid >> 3;
  const int scs = (tid & 7) ^ (srow & 7);
  const __bf16* Ag = A + (size_t)(m0 + srow) * K + scs * 8;
  const __bf16* Wg = W + (size_t)(n0 + srow) * K + scs * 8;

#define G_STAGE(k0_, b_)                                                        \
  { __bf16* As_ = AsB + (b_) * (TM + TN) * 64;                                  \
    __bf16* Bs_ = As_ + TM * 64;                                                \
    _Pragma("unroll")                                                           \
    for (int i = 0; i < TM / 32; ++i)                                           \
      gload_lds16(Ag + (size_t)(i * 32) * K + (k0_), &As_[(i * 256 + tid) * 8]);\
    _Pragma("unroll")                                                           \
    for (int i = 0; i < TN / 32; ++i)                                           \
      gload_lds16(Wg + (size_t)(i * 32) * K + (k0_), &Bs_[(i * 256 + tid) * 8]); }

  const int NT = K >> 6;
  G_STAGE(0, 0)
  __syncthreads();

  for (int t = 0; t < NT; ++t) {
    if (t + 1 < NT) G_STAGE((t + 1) << 6, (t + 1) & 1)
    const __bf16* As_ = AsB + (t & 1) * (TM + TN) * 64;
    const __bf16* Bs_ = As_ + TM * 64;
#pragma unroll
    for (int hk = 0; hk < 2; ++hk) {
      const int ph = ((hk * 4 + quad) ^ swz) * 8;
      bf16x8 af[MS], bfr[NS];
#pragma unroll
      for (int i = 0; i < MS; ++i)
        af[i] = *(const bf16x8*)&As_[(wm + i * 16 + l16) * 64 + ph];
#pragma unroll
      for (int j = 0; j < NS; ++j)
        bfr[j] = *(const bf16x8*)&Bs_[(wn + j * 16 + l16) * 64 + ph];
#pragma unroll
      for (int i = 0; i < MS; ++i)
#pragma unroll
        for (int j = 0; j < NS; ++j)
          acc[i][j] = __builtin_amdgcn_mfma_f32_16x16x32_bf16(af[i], bfr[j], acc[i][j], 0, 0, 0);
    }
    __syncthreads();   // (a) everyone done with buf t; (b) stage(t+1) drained
  }

  // ---- epilogue: stage C tile in LDS (aliases staging bufs), 16B stores ----
  if (MODE == 0) {
    float* Cs = (float*)smem;          // [TM][TN+4]
    constexpr int cst = TN + 4;
#pragma unroll
    for (int j = 0; j < NS; ++j) {
      const int c = wn + j * 16 + l16;
      const float bv_ = bias[n0 + c];
#pragma unroll
      for (int i = 0; i < MS; ++i) {
        const int r0 = wm + i * 16 + quad * 4;
#pragma unroll
        for (int g = 0; g < 4; ++g)
          Cs[(r0 + g) * cst + c] = acc[i][j][g] + bv_;
      }
    }
    __syncthreads();
    constexpr int passes = TM * TN / (256 * 4);
#pragma unroll
    for (int p = 0; p < passes; ++p) {
      const int slot = p * 256 + tid;
      const int row = slot / (TN / 4);
      const int col4 = (slot % (TN / 4)) * 4;
      f32x4 v = *(const f32x4*)&Cs[row * cst + col4];
      *(f32x4*)&Cf[(size_t)(m0 + row) * ldc + n0 + col4] = v;
    }
  } else {
    __bf16* Cs = (__bf16*)smem;
    constexpr int cst = TN + 8;
    const bool vtile = (n0 >= 2048);
    if (!vtile) {
#pragma unroll
      for (int j = 0; j < NS; ++j) {
        const int c = wn + j * 16 + l16;
        const float bv_ = bias[n0 + c];
        const float sc = ((n0 + c) < 1024) ? SCL : 1.0f;
#pragma unroll
        for (int i = 0; i < MS; ++i) {
          const int r0 = wm + i * 16 + quad * 4;
#pragma unroll
          for (int g = 0; g < 4; ++g)
            Cs[(r0 + g) * cst + c] = (__bf16)((acc[i][j][g] + bv_) * sc);
        }
      }
      __syncthreads();
      constexpr int passes = TM * TN / (256 * 8);
#pragma unroll
      for (int p = 0; p < passes; ++p) {
        const int slot = p * 256 + tid;
        const int row = slot / (TN / 8);
        const int col8 = (slot % (TN / 8)) * 8;
        bf16x8 v = *(const bf16x8*)&Cs[row * cst + col8];
        *(bf16x8*)&Cb[(size_t)(m0 + row) * 3072 + n0 + col8] = v;
      }
    } else {
      constexpr int cstT = TM + 8;
#pragma unroll
      for (int j = 0; j < NS; ++j) {
        const int c = wn + j * 16 + l16;
        const float bv_ = bias[n0 + c];
#pragma unroll
        for (int i = 0; i < MS; ++i) {
          const int r0 = wm + i * 16 + quad * 4;
#pragma unroll
          for (int g = 0; g < 4; ++g)
            Cs[c * cstT + r0 + g] = (__bf16)(acc[i][j][g] + bv_);
        }
      }
      __syncthreads();
      const int bb = m0 >> 11, ml = m0 & 2047;
      constexpr int passes = TM * TN / (256 * 8);
#pragma unroll
      for (int p = 0; p < passes; ++p) {
        const int slot = p * 256 + tid;
        const int dd = slot / (TM / 8);
        const int ss8 = (slot % (TM / 8)) * 8;
        bf16x8 v = *(const bf16x8*)&Cs[dd * cstT + ss8];
        const int c2 = n0 - 2048 + dd;
        const int hh = c2 >> 6, ddd = c2 & 63;
        *(bf16x8*)&vT[((size_t)(bb * 16 + hh) * 64 + ddd) * 2048 + ml + ss8] = v;
      }
    }
  }
}

// ---------------- MFMA flash attention, S^T formulation (r10, unchanged) ----
__global__ __launch_bounds__(256) void attn_mfma(
    const __bf16* __restrict__ qkv, const __bf16* __restrict__ vT,
    __bf16* __restrict__ zb)
{
  __shared__ __bf16 Qs[64 * 64];      // Q; later per-wave P slices
  __shared__ __bf16 Ks[2][64 * 64];
  __shared__ __bf16 Vs[3][64 * 64];   // [d][k] (from vT)

  const int tid = threadIdx.x;
  const int lane = tid & 63, wave = tid >> 6;
  const int l16 = lane & 15, quad = lane >> 4;
  const int bx = blockIdx.x;
  const int qt = 31 - (bx >> 5);       // heavy q-tiles dispatched first
  const int bh = bx & 31;
  const int h = bh & 15, b = bh >> 4;
  const int q0 = qt * 64;

  const __bf16* qg = qkv + (size_t)b * 2048 * 3072 + h * 64;
  const __bf16* kg = qg + 1024;
  const __bf16* vg = vT + (size_t)bh * 64 * 2048;

#define STAGE_KV(kt_, kbuf, vbuf)                                               \
  { const int kn = (kt_) * 64;                                                  \
    _Pragma("unroll")                                                           \
    for (int i = 0; i < 2; ++i) {                                               \
      int slot = i * 256 + tid;                                                 \
      int row = slot >> 3, ph2 = slot & 7;                                      \
      int cs = ph2 ^ (row & 7);                                                 \
      gload_lds16(kg + (size_t)(kn + row) * 3072 + cs * 8, &Ks[kbuf][slot * 8]);\
      gload_lds16(vg + (size_t)row * 2048 + kn + cs * 8, &Vs[vbuf][slot * 8]);  \
    } }

  // prologue: Q + K/V tile 0
#pragma unroll
  for (int i = 0; i < 2; ++i) {
    int slot = i * 256 + tid;
    int row = slot >> 3, ph2 = slot & 7;
    int cs = ph2 ^ (row & 7);
    gload_lds16(qg + (size_t)(q0 + row) * 3072 + cs * 8, &Qs[slot * 8]);
  }
  STAGE_KV(0, 0, 0)
  __syncthreads();

  const int swz = l16 & 7;
  const int sw0 = ((quad) ^ swz) * 8;
  const int sw1 = ((quad + 4) ^ swz) * 8;
  const int mrow = wave * 16 + l16;

  // Q fragments (loop-invariant), used as the B operand of S^T = K.Q^T
  bf16x8 qf0 = *(const bf16x8*)&Qs[mrow * 64 + sw0];
  bf16x8 qf1 = *(const bf16x8*)&Qs[mrow * 64 + sw1];
  __bf16* P = &Qs[wave * 16 * 64];    // this wave's own 16x64 slice

  // ones B-frag: B[n=0][k]=1 -> col 0 of Ol = row-sum of P (the l vector)
  bf16x8 onesf;
  {
    __bf16 ov = (l16 == 0) ? (__bf16)1.0f : (__bf16)0.0f;
#pragma unroll
    for (int i = 0; i < 8; ++i) onesf[i] = ov;
  }

  const f32x4 zero = {0.f, 0.f, 0.f, 0.f};
  f32x4 O[4], Ol = zero;
#pragma unroll
  for (int j = 0; j < 4; ++j) O[j] = zero;
  f32x4 s_cur[4], s_next[4];   // S^T: lane holds [key=m*16+quad*4+g][q=l16]

#define S_TILE(sdst, kb)                                                        \
  { _Pragma("unroll")                                                           \
    for (int m = 0; m < 4; ++m) sdst[m] = zero;                                 \
    _Pragma("unroll")                                                           \
    for (int m = 0; m < 4; ++m) {                                               \
      bf16x8 kf0 = *(const bf16x8*)&Ks[kb][(m * 16 + l16) * 64 + sw0];          \
      sdst[m] = __builtin_amdgcn_mfma_f32_16x16x32_bf16(kf0, qf0, sdst[m],0,0,0);\
      bf16x8 kf1 = *(const bf16x8*)&Ks[kb][(m * 16 + l16) * 64 + sw1];          \
      sdst[m] = __builtin_amdgcn_mfma_f32_16x16x32_bf16(kf1, qf1, sdst[m],0,0,0);\
    } }

#define EXP_P(s, DIAG)                                                          \
  { _Pragma("unroll")                                                           \
    for (int m = 0; m < 4; ++m) {                                               \
      const int kl = m * 16 + quad * 4;                                         \
      bf16x4 st;                                                                \
      _Pragma("unroll")                                                         \
      for (int g = 0; g < 4; ++g) {                                             \
        float p = __builtin_exp2f(s[m][g]);                                     \
        if (DIAG && (kl + g) > (wave * 16 + l16)) p = 0.f;                      \
        st[g] = (__bf16)p;                                                      \
      }                                                                         \
      *(bf16x4*)&P[l16 * 64 + (((2 * m + (quad >> 1)) ^ swz) * 8) + (quad & 1) * 4] = st; \
    } }

#define PV_TILE(vb)                                                             \
  { bf16x8 pf0 = *(const bf16x8*)&P[l16 * 64 + sw0];                            \
    bf16x8 pf1 = *(const bf16x8*)&P[l16 * 64 + sw1];                            \
    _Pragma("unroll")                                                           \
    for (int j = 0; j < 4; ++j) {                                               \
      bf16x8 vf0 = *(const bf16x8*)&Vs[vb][(j * 16 + l16) * 64 + sw0];          \
      O[j] = __builtin_amdgcn_mfma_f32_16x16x32_bf16(pf0, vf0, O[j], 0, 0, 0);  \
      bf16x8 vf1 = *(const bf16x8*)&Vs[vb][(j * 16 + l16) * 64 + sw1];          \
      O[j] = __builtin_amdgcn_mfma_f32_16x16x32_bf16(pf1, vf1, O[j], 0, 0, 0);  \
    }                                                                           \
    Ol = __builtin_amdgcn_mfma_f32_16x16x32_bf16(pf0, onesf, Ol, 0, 0, 0);      \
    Ol = __builtin_amdgcn_mfma_f32_16x16x32_bf16(pf1, onesf, Ol, 0, 0, 0); }

  // pipeline prologue: stage tile 1, compute S^T(0)
  if (qt > 0) STAGE_KV(1, 1, 1)
  S_TILE(s_cur, 0)
  if (qt > 0) __syncthreads();   // drains stage(1)

  for (int t = 0; t < qt; ++t) {
    EXP_P(s_cur, false)                    // VALU of tile t ...
    S_TILE(s_next, (t + 1) & 1)            // ... overlaps MFMA of tile t+1
    PV_TILE(t % 3)
    if (t + 2 <= qt) STAGE_KV(t + 2, t & 1, (t + 2) % 3)
    __syncthreads();
#pragma unroll
    for (int m = 0; m < 4; ++m) s_cur[m] = s_next[m];
  }
  // diagonal (masked) tile
  EXP_P(s_cur, true)
  PV_TILE(qt % 3)

  // epilogue: l lives in col 0 of Ol (lanes l16==0); broadcast within quad
  const int rq = q0 + wave * 16 + quad * 4;
#pragma unroll
  for (int g = 0; g < 4; ++g) {
    const float lv = __shfl(Ol[g], quad * 16);
    const float inv = 1.0f / lv;
    const size_t rb = (size_t)(b * 2048 + rq + g) * 1024 + h * 64 + l16;
#pragma unroll
    for (int j = 0; j < 4; ++j)
      zb[rb + j * 16] = (__bf16)(O[j][g] * inv);
  }
}

// ---------------- launch ----------------
extern "C" void kernel_launch(void* const* d_in, const int* in_sizes, int n_in,
                              void* d_out, int out_size, void* d_ws, size_t ws_size,
                              hipStream_t stream) {
  (void)in_sizes; (void)n_in; (void)out_size; (void)ws_size;
  const float* x  = (const float*)d_in[0];
  const float* Wq = (const float*)d_in[1];
  const float* bq = (const float*)d_in[2];
  const float* Wk = (const float*)d_in[3];
  const float* bk = (const float*)d_in[4];
  const float* Wv = (const float*)d_in[5];
  const float* bv = (const float*)d_in[6];
  const float* Wo = (const float*)d_in[7];
  const float* bo = (const float*)d_in[8];

  char* ws = (char*)d_ws;
  __bf16* xb   = (__bf16*)(ws);                        // 8 MB
  __bf16* wqkv = (__bf16*)(ws + (8ull  << 20));        // 6 MB
  __bf16* wob  = (__bf16*)(ws + (14ull << 20));        // 2 MB
  float*  bqkv = (float*) (ws + (16ull << 20));        // 12 KB
  __bf16* qkv  = (__bf16*)(ws + (17ull << 20));        // 24 MB
  __bf16* vT   = (__bf16*)(ws + (41ull << 20));        // 8 MB  [bh][64][2048]
  __bf16* zb   = (__bf16*)(ws + (49ull << 20));        // 8 MB  (total 57 MB)

  cvt_kernel<<<4097, 256, 0, stream>>>(x, Wq, Wk, Wv, Wo, bq, bk, bv,
                                       xb, wqkv, wob, bqkv);
  gemm_k<128, 128, 1><<<dim3(24, 32), 256, 0, stream>>>(
      xb, wqkv, bqkv, nullptr, qkv, vT, Mx, 3072, 1024, 0);
  attn_mfma<<<1024, 256, 0, stream>>>(qkv, vT, zb);
  gemm_k<128, 64, 0><<<dim3(16, 32), 256, 0, stream>>>(
      zb, wob, bo, (float*)d_out, nullptr, nullptr, Mx, 1024, 1024, 1024);
}